// Round 14
// baseline (254.902 us; speedup 1.0000x reference)
//
#include <hip/hip_runtime.h>
#include <hip/hip_bf16.h>
#include <math.h>

#define D    64
#define F3   192
#define NPB  256          // nodes per bucket (local dst = 8 bits)
#define LBITS 8
#define SBITS 17          // src id fits in 17 bits (N=100000 < 131072)
#define NBLK 256          // edge blocks for binning passes
#define SCAN_CHUNK 2048   // 256 threads * 8 elements (== 1<<11)
#define BUCKET_PAD 1800   // per-bucket ssrc slack (multiple of 8)
#define SSRC_CAP   2000000

using bf16x8 = __attribute__((ext_vector_type(8))) short;
using f32x4  = __attribute__((ext_vector_type(4))) float;

__device__ __forceinline__ ushort f2bf(float f) {
    __hip_bfloat16 h = __float2bfloat16(f);
    return *reinterpret_cast<ushort*>(&h);
}
__device__ __forceinline__ float bf2f(ushort u) {
    unsigned v = ((unsigned)u) << 16;
    return __uint_as_float(v);
}

// ---------------- A1 + pre-cast: hist | xcast | wcast by block range -------
__global__ __launch_bounds__(256) void k_cast_hist(
    const float* __restrict__ x, ushort* __restrict__ xb, int n4,
    const float* __restrict__ W, ushort* __restrict__ Wb, int nW,
    const int* __restrict__ dstv, unsigned* __restrict__ bcntT,
    int E, int EPB, int NB, int castBlocks)
{
    int bid = blockIdx.x;
    if (bid < NBLK) {
        __shared__ unsigned h[512];
        for (int i = threadIdx.x; i < NB; i += 256) h[i] = 0;
        __syncthreads();
        int lo = bid * EPB, hi = min(E, lo + EPB);
        for (int e = lo + threadIdx.x; e < hi; e += 256)
            atomicAdd(&h[((unsigned)dstv[e]) >> LBITS], 1u);
        __syncthreads();
        for (int i = threadIdx.x; i < NB; i += 256)
            bcntT[(size_t)i * NBLK + bid] = h[i];
    } else if (bid < NBLK + castBlocks) {
        int i = (bid - NBLK) * 256 + threadIdx.x;
        if (i < n4) {
            float4 v = *reinterpret_cast<const float4*>(x + (size_t)i * 4);
            ushort4 u = { f2bf(v.x), f2bf(v.y), f2bf(v.z), f2bf(v.w) };
            *reinterpret_cast<ushort4*>(xb + (size_t)i * 4) = u;
        }
    } else {
        for (int i = threadIdx.x; i < nW; i += 256) Wb[i] = f2bf(W[i]);
    }
}

// ---------------- A2: chunked exclusive scan of the [bucket][block] matrix --
__global__ __launch_bounds__(256) void k_chunk_scan(
    const unsigned* __restrict__ cnt, unsigned* __restrict__ offs,
    unsigned* __restrict__ partials, int N)
{
    __shared__ unsigned ts[256];
    int t = threadIdx.x;
    int ebase = blockIdx.x * SCAN_CHUNK + t * 8;
    unsigned v[8];
    unsigned s = 0;
    #pragma unroll
    for (int j = 0; j < 8; ++j) {
        unsigned c = (ebase + j < N) ? cnt[ebase + j] : 0u;
        v[j] = s; s += c;
    }
    ts[t] = s;
    __syncthreads();
    #pragma unroll
    for (int off = 1; off < 256; off <<= 1) {
        unsigned add = (t >= off) ? ts[t - off] : 0u;
        __syncthreads();
        ts[t] += add;
        __syncthreads();
    }
    unsigned tb = (t > 0) ? ts[t - 1] : 0u;
    #pragma unroll
    for (int j = 0; j < 8; ++j)
        if (ebase + j < N) offs[ebase + j] = tb + v[j];
    if (t == 255) partials[blockIdx.x] = ts[255];
}

// inline exclusive scan of chunk partials (<=64 entries) into LDS
__device__ __forceinline__ void scan_partials_lds(
    const unsigned* __restrict__ partials, unsigned* psc, int n, int t)
{
    __shared__ unsigned raw[64];
    if (t < n) raw[t] = partials[t];
    __syncthreads();
    if (t == 0) {
        unsigned s = 0;
        for (int i = 0; i < n; ++i) { unsigned c = raw[i]; psc[i] = s; s += c; }
    }
    __syncthreads();
}

// ---------------- A3: scatter edges into bucket-grouped storage -------------
__global__ __launch_bounds__(256) void k_bin_scatter(
    const int* __restrict__ srcv, const int* __restrict__ dstv,
    const unsigned* __restrict__ bbaseT, const unsigned* __restrict__ partials,
    int nChunks, unsigned* __restrict__ binned, int E, int EPB, int NB)
{
    __shared__ unsigned cur[512];
    __shared__ unsigned psc[64];
    int t = threadIdx.x;
    scan_partials_lds(partials, psc, nChunks, t);
    for (int i = t; i < NB; i += 256) {
        unsigned idx = (unsigned)i * NBLK + blockIdx.x;
        cur[i] = bbaseT[idx] + psc[idx >> 11];
    }
    __syncthreads();
    int lo = blockIdx.x * EPB, hi = min(E, lo + EPB);
    for (int e = lo + t; e < hi; e += 256) {
        unsigned d = (unsigned)dstv[e];
        unsigned s = (unsigned)srcv[e];
        unsigned p = atomicAdd(&cur[d >> LBITS], 1u);
        binned[p] = ((d & (NPB - 1u)) << SBITS) | s;
    }
}

// ---------------- A4: per-bucket CSR with 8-aligned padded node segments ----
__global__ __launch_bounds__(256) void k_bucket_csr(
    const unsigned* __restrict__ binned, const unsigned* __restrict__ bbaseT,
    const unsigned* __restrict__ partials, int nChunks,
    unsigned* __restrict__ offs, unsigned* __restrict__ cnt,
    unsigned* __restrict__ ssrc, int E, int NB, int N)
{
    __shared__ unsigned c[256];
    __shared__ unsigned ts[256];
    __shared__ unsigned psc[64];
    int k = blockIdx.x;
    int t = threadIdx.x;
    scan_partials_lds(partials, psc, nChunks, t);

    unsigned i0 = (unsigned)k * NBLK;
    unsigned bstart = bbaseT[i0] + psc[i0 >> 11];
    unsigned bend;
    if (k + 1 < NB) {
        unsigned i1 = (unsigned)(k + 1) * NBLK;
        bend = bbaseT[i1] + psc[i1 >> 11];
    } else bend = (unsigned)E;
    unsigned bstartPad = ((bstart + 7u) & ~7u) + (unsigned)BUCKET_PAD * k;

    c[t] = 0;
    __syncthreads();
    for (unsigned e = bstart + t; e < bend; e += 256)
        atomicAdd(&c[binned[e] >> SBITS], 1u);
    __syncthreads();

    unsigned myc  = c[t];
    unsigned mycp = (myc + 7u) & ~7u;        // padded to 8
    ts[t] = mycp;
    __syncthreads();
    #pragma unroll
    for (int off = 1; off < 256; off <<= 1) {
        unsigned add = (t >= off) ? ts[t - off] : 0u;
        __syncthreads();
        ts[t] += add;
        __syncthreads();
    }
    unsigned exclp = t ? ts[t - 1] : 0u;
    unsigned stPad = bstartPad + exclp;

    int gn = k * NPB + t;
    if (gn < N) { offs[gn] = stPad; cnt[gn] = myc; }

    c[t] = exclp;          // local padded cursor
    __syncthreads();
    for (unsigned e = bstart + t; e < bend; e += 256) {
        unsigned u  = binned[e];
        unsigned ld = u >> SBITS;
        unsigned r  = atomicAdd(&c[ld], 1u);
        ssrc[bstartPad + r] = u & ((1u << SBITS) - 1u);
    }
    __syncthreads();
    // pad fill: duplicate last id (sum compensated in gather; max unaffected)
    if (myc && mycp > myc) {
        unsigned lastId = ssrc[stPad + myc - 1];
        for (unsigned j = myc; j < mycp; ++j) ssrc[stPad + j] = lastId;
    }
}

// ---------------- Phase B: FUSED gather + MFMA MLP ----------------
// Wave = one 16-node tile (grid-stride, N%16==0). Per node: r13's
// channel-pair gather (lanes 0-31 even edge, 32-63 odd edge; one dword
// load = 2 bf16 channels; 16 edges in flight). Result dword written to a
// WAVE-PRIVATE LDS tile [16 nodes][64 dwords] with XOR swizzle
// (dword ^= (nd&7)<<2) so the epilogue ds_read_b128 A-frag reads hit the
// optimal 8-lanes-per-16B-slot pattern (unswizzled would be 16-way).
// No __syncthreads anywhere: LDS region is wave-private, compiler orders
// via lgkmcnt. Epilogue: A-frags (sum/max) from LDS, mean frag = sum*inv
// (A-row = node = lane&15 -> inv is a per-lane scalar), B-frags from the
// L1-resident 24KB Wb, 4 col-blocks x 6 mfma_f32_16x16x32_bf16.
__global__ __launch_bounds__(256) void k_gather_mlp(
    const ushort*   __restrict__ xb,      // [N][64] bf16
    const unsigned* __restrict__ ssrc,
    const unsigned* __restrict__ offs,
    const unsigned* __restrict__ cnt,
    const ushort*   __restrict__ Wb,      // [64][192] bf16
    const float*    __restrict__ bias,    // [64]
    float*          __restrict__ out,     // [N][64]
    int N)
{
    __shared__ unsigned tile[4][16 * 64];   // per-wave swizzled [node][dword]
    __shared__ float    invl[4][16];

    const unsigned* xw = reinterpret_cast<const unsigned*>(xb);  // row = 32 dwords

    int tid  = threadIdx.x;
    unsigned lane = tid & 63;
    unsigned l31  = lane & 31;
    bool     hi   = lane >= 32;
    int wv   = tid >> 6;
    unsigned* my = &tile[wv][0];

    int l16 = (int)(lane & 15);
    int kq  = (int)(lane >> 4);          // 0..3
    int kb  = kq << 3;

    // hoist per-lane bias (col = cb*16 + l16)
    float bo0 = bias[l16], bo1 = bias[16 + l16];
    float bo2 = bias[32 + l16], bo3 = bias[48 + l16];

    int ntiles = N >> 4;                 // N divisible by 16
    for (int t = blockIdx.x; t < ntiles; t += gridDim.x) {
        int n0 = t << 4;

        // ---- gather 16 nodes (wave-sequential; loads deeply in flight) ----
        for (int nd = 0; nd < 16; ++nd) {
            int n = n0 + nd;
            unsigned st  = offs[n];
            unsigned dg  = cnt[n];
            unsigned dgp = (dg + 7u) & ~7u;

            float se0 = 0.f, so0 = 0.f, se1 = 0.f, so1 = 0.f;
            float me0 = -INFINITY, mo0 = -INFINITY, me1 = -INFINITY, mo1 = -INFINITY;

            unsigned i = 0;
            for (; i + 16 <= dgp; i += 16) {          // 16 edges = 8 pair-loads
                uint4 ia = *reinterpret_cast<const uint4*>(ssrc + st + i);
                uint4 ib = *reinterpret_cast<const uint4*>(ssrc + st + i + 4);
                uint4 ic = *reinterpret_cast<const uint4*>(ssrc + st + i + 8);
                uint4 id = *reinterpret_cast<const uint4*>(ssrc + st + i + 12);
                unsigned p0 = hi ? ia.y : ia.x;
                unsigned p1 = hi ? ia.w : ia.z;
                unsigned p2 = hi ? ib.y : ib.x;
                unsigned p3 = hi ? ib.w : ib.z;
                unsigned p4 = hi ? ic.y : ic.x;
                unsigned p5 = hi ? ic.w : ic.z;
                unsigned p6 = hi ? id.y : id.x;
                unsigned p7 = hi ? id.w : id.z;
                unsigned w0 = xw[(p0 << 5) | l31];
                unsigned w1 = xw[(p1 << 5) | l31];
                unsigned w2 = xw[(p2 << 5) | l31];
                unsigned w3 = xw[(p3 << 5) | l31];
                unsigned w4 = xw[(p4 << 5) | l31];
                unsigned w5 = xw[(p5 << 5) | l31];
                unsigned w6 = xw[(p6 << 5) | l31];
                unsigned w7 = xw[(p7 << 5) | l31];
                #pragma unroll
                for (int j = 0; j < 8; ++j) {
                    unsigned w = (j==0)?w0:(j==1)?w1:(j==2)?w2:(j==3)?w3:
                                 (j==4)?w4:(j==5)?w5:(j==6)?w6:w7;
                    float fe = __uint_as_float(w << 16);
                    float fo = __uint_as_float(w & 0xFFFF0000u);
                    if (j & 1) {
                        se1 += fe; so1 += fo;
                        me1 = fmaxf(me1, fe); mo1 = fmaxf(mo1, fo);
                    } else {
                        se0 += fe; so0 += fo;
                        me0 = fmaxf(me0, fe); mo0 = fmaxf(mo0, fo);
                    }
                }
            }
            if (i < dgp) {                             // one 8-edge batch
                uint4 ia = *reinterpret_cast<const uint4*>(ssrc + st + i);
                uint4 ib = *reinterpret_cast<const uint4*>(ssrc + st + i + 4);
                unsigned p0 = hi ? ia.y : ia.x;
                unsigned p1 = hi ? ia.w : ia.z;
                unsigned p2 = hi ? ib.y : ib.x;
                unsigned p3 = hi ? ib.w : ib.z;
                unsigned w0 = xw[(p0 << 5) | l31];
                unsigned w1 = xw[(p1 << 5) | l31];
                unsigned w2 = xw[(p2 << 5) | l31];
                unsigned w3 = xw[(p3 << 5) | l31];
                #pragma unroll
                for (int j = 0; j < 4; ++j) {
                    unsigned w = (j==0)?w0:(j==1)?w1:(j==2)?w2:w3;
                    float fe = __uint_as_float(w << 16);
                    float fo = __uint_as_float(w & 0xFFFF0000u);
                    if (j & 1) {
                        se1 += fe; so1 += fo;
                        me1 = fmaxf(me1, fe); mo1 = fmaxf(mo1, fo);
                    } else {
                        se0 += fe; so0 += fo;
                        me0 = fmaxf(me0, fe); mo0 = fmaxf(mo0, fo);
                    }
                }
            }

            float se = se0 + se1, so = so0 + so1;
            float me = fmaxf(me0, me1), mo = fmaxf(mo0, mo1);
            se += __shfl_xor(se, 32);
            so += __shfl_xor(so, 32);
            me = fmaxf(me, __shfl_xor(me, 32));
            mo = fmaxf(mo, __shfl_xor(mo, 32));

            unsigned p = dgp - dg;
            if (p && dg) {                             // pad compensation
                unsigned lastId = ssrc[st + dg - 1];
                unsigned w = xw[(lastId << 5) | l31];
                se -= (float)p * __uint_as_float(w << 16);
                so -= (float)p * __uint_as_float(w & 0xFFFF0000u);
            }
            if (!dg) { me = 0.0f; mo = 0.0f; }

            float v0 = hi ? me : se;                   // lanes 0-31: sum dword
            float v1 = hi ? mo : so;                   // lanes 32-63: max dword
            unsigned outwd = ((unsigned)f2bf(v0)) | (((unsigned)f2bf(v1)) << 16);
            my[(nd << 6) | (lane ^ (((unsigned)nd & 7u) << 2))] = outwd;
            if (lane == 0) invl[wv][nd] = dg ? 1.0f / (float)dg : 0.0f;
        }

        // ---- MFMA epilogue (wave-private; lgkmcnt orders LDS) ----
        float inv = invl[wv][l16];

        // A-frag read: slice s (0,1=sum; 2,3=max): dwords s*16 + kq*4 .. +3
        // swizzled with the write's XOR.
        bf16x8 aS0, aS1, aX0, aX1;
        {
            unsigned sw = ((unsigned)(l16 & 7)) << 2;
            unsigned row = (unsigned)l16 << 6;
            aS0 = *reinterpret_cast<const bf16x8*>(&my[row | (((unsigned)(0*16 + kq*4)) ^ sw)]);
            aS1 = *reinterpret_cast<const bf16x8*>(&my[row | (((unsigned)(1*16 + kq*4)) ^ sw)]);
            aX0 = *reinterpret_cast<const bf16x8*>(&my[row | (((unsigned)(2*16 + kq*4)) ^ sw)]);
            aX1 = *reinterpret_cast<const bf16x8*>(&my[row | (((unsigned)(3*16 + kq*4)) ^ sw)]);
        }
        bf16x8 aM0, aM1;
        #pragma unroll
        for (int j = 0; j < 8; ++j) {
            aM0[j] = (short)f2bf(bf2f((ushort)aS0[j]) * inv);
            aM1[j] = (short)f2bf(bf2f((ushort)aS1[j]) * inv);
        }

        #pragma unroll
        for (int cb = 0; cb < 4; ++cb) {
            int col = (cb << 4) + l16;
            const ushort* wp = Wb + (size_t)col * F3 + kb;
            bf16x8 bS0 = *reinterpret_cast<const bf16x8*>(wp);
            bf16x8 bS1 = *reinterpret_cast<const bf16x8*>(wp + 32);
            bf16x8 bM0 = *reinterpret_cast<const bf16x8*>(wp + 64);
            bf16x8 bM1 = *reinterpret_cast<const bf16x8*>(wp + 96);
            bf16x8 bX0 = *reinterpret_cast<const bf16x8*>(wp + 128);
            bf16x8 bX1 = *reinterpret_cast<const bf16x8*>(wp + 160);
            float bo = (cb == 0) ? bo0 : (cb == 1) ? bo1 : (cb == 2) ? bo2 : bo3;

            f32x4 acc = { bo, bo, bo, bo };
            acc = __builtin_amdgcn_mfma_f32_16x16x32_bf16(aS0, bS0, acc, 0, 0, 0);
            acc = __builtin_amdgcn_mfma_f32_16x16x32_bf16(aS1, bS1, acc, 0, 0, 0);
            acc = __builtin_amdgcn_mfma_f32_16x16x32_bf16(aM0, bM0, acc, 0, 0, 0);
            acc = __builtin_amdgcn_mfma_f32_16x16x32_bf16(aM1, bM1, acc, 0, 0, 0);
            acc = __builtin_amdgcn_mfma_f32_16x16x32_bf16(aX0, bX0, acc, 0, 0, 0);
            acc = __builtin_amdgcn_mfma_f32_16x16x32_bf16(aX1, bX1, acc, 0, 0, 0);

            int rbase = n0 + (kq << 2);
            #pragma unroll
            for (int r = 0; r < 4; ++r)
                out[(size_t)(rbase + r) * D + col] = acc[r];
        }
    }
}

extern "C" void kernel_launch(void* const* d_in, const int* in_sizes, int n_in,
                              void* d_out, int out_size, void* d_ws, size_t ws_size,
                              hipStream_t stream)
{
    const float* x  = (const float*)d_in[0];
    const int*   ei = (const int*)d_in[1];
    const float* W  = (const float*)d_in[2];
    const float* b  = (const float*)d_in[3];
    float* out = (float*)d_out;

    int N = in_sizes[0] / D;
    int E = in_sizes[1] / 2;
    const int* srcv = ei;
    const int* dstv = ei + E;

    int NB  = (N + NPB - 1) / NPB;          // 391 buckets
    int EPB = (E + NBLK - 1) / NBLK;
    int M   = NB * NBLK;                    // 100096

    unsigned* bcntT    = (unsigned*)d_ws;          // [M]       400KB
    unsigned* bbaseT   = bcntT + M;                // [M]       400KB
    unsigned* partials = bbaseT + M;               // [64]
    unsigned* offs     = partials + 64;            // [N]       400KB
    unsigned* cnt      = offs + N;                 // [N]       400KB
    unsigned* ssrc     = cnt + N;                  // [SSRC_CAP] 8MB (padded)
    ushort*   xb       = (ushort*)(ssrc + SSRC_CAP);   // [N*64]  12.8MB
    ushort*   Wb       = xb + (size_t)N * D;           // [64*192] 24KB
    unsigned* binned   = (unsigned*)(Wb + (size_t)D * F3);  // [E] 5MB

    int nChunksM  = (M + SCAN_CHUNK - 1) / SCAN_CHUNK;  // 49
    int n4        = N * D / 4;
    int castBlocks = (n4 + 255) / 256;

    k_cast_hist<<<NBLK + castBlocks + 1, 256, 0, stream>>>(
        x, xb, n4, W, Wb, D * F3, dstv, bcntT, E, EPB, NB, castBlocks);
    k_chunk_scan<<<nChunksM, 256, 0, stream>>>(bcntT, bbaseT, partials, M);
    k_bin_scatter<<<NBLK, 256, 0, stream>>>(srcv, dstv, bbaseT, partials,
                                            nChunksM, binned, E, EPB, NB);
    k_bucket_csr<<<NB, 256, 0, stream>>>(binned, bbaseT, partials, nChunksM,
                                         offs, cnt, ssrc, E, NB, N);
    k_gather_mlp<<<2048, 256, 0, stream>>>(xb, ssrc, offs, cnt, Wb, b, out, N);
}

// Round 15
// 114.425 us; speedup vs baseline: 2.2277x; 2.2277x over previous
//
#include <hip/hip_runtime.h>
#include <hip/hip_bf16.h>
#include <math.h>

#define D    64
#define F3   192
#define FS   128          // stored feats channels: [sum(64) | max(64)]
#define NPB  256          // nodes per bucket (local dst = 8 bits)
#define LBITS 8
#define SBITS 17          // src id fits in 17 bits (N=100000 < 131072)
#define NBLK 256          // edge blocks for binning passes
#define SCAN_CHUNK 2048   // 256 threads * 8 elements (== 1<<11)
#define BUCKET_PAD 1800   // per-bucket ssrc slack: 256 nodes * 7 + align
#define SSRC_CAP   2000000

using bf16x8 = __attribute__((ext_vector_type(8))) short;
using f32x4  = __attribute__((ext_vector_type(4))) float;

__device__ __forceinline__ ushort f2bf(float f) {
    __hip_bfloat16 h = __float2bfloat16(f);
    return *reinterpret_cast<ushort*>(&h);
}
__device__ __forceinline__ float bf2f(ushort u) {
    unsigned v = ((unsigned)u) << 16;
    return __uint_as_float(v);
}

// ---------------- A1 + pre-cast: hist | xcast | wcast by block range -------
__global__ __launch_bounds__(256) void k_cast_hist(
    const float* __restrict__ x, ushort* __restrict__ xb, int n4,
    const float* __restrict__ W, ushort* __restrict__ Wb, int nW,
    const int* __restrict__ dstv, unsigned* __restrict__ bcntT,
    int E, int EPB, int NB, int castBlocks)
{
    int bid = blockIdx.x;
    if (bid < NBLK) {
        __shared__ unsigned h[512];
        for (int i = threadIdx.x; i < NB; i += 256) h[i] = 0;
        __syncthreads();
        int lo = bid * EPB, hi = min(E, lo + EPB);
        for (int e = lo + threadIdx.x; e < hi; e += 256)
            atomicAdd(&h[((unsigned)dstv[e]) >> LBITS], 1u);
        __syncthreads();
        for (int i = threadIdx.x; i < NB; i += 256)
            bcntT[(size_t)i * NBLK + bid] = h[i];
    } else if (bid < NBLK + castBlocks) {
        int i = (bid - NBLK) * 256 + threadIdx.x;
        if (i < n4) {
            float4 v = *reinterpret_cast<const float4*>(x + (size_t)i * 4);
            ushort4 u = { f2bf(v.x), f2bf(v.y), f2bf(v.z), f2bf(v.w) };
            *reinterpret_cast<ushort4*>(xb + (size_t)i * 4) = u;
        }
    } else {
        for (int i = threadIdx.x; i < nW; i += 256) Wb[i] = f2bf(W[i]);
    }
}

// ---------------- A2: chunked exclusive scan of the [bucket][block] matrix --
__global__ __launch_bounds__(256) void k_chunk_scan(
    const unsigned* __restrict__ cnt, unsigned* __restrict__ offs,
    unsigned* __restrict__ partials, int N)
{
    __shared__ unsigned ts[256];
    int t = threadIdx.x;
    int ebase = blockIdx.x * SCAN_CHUNK + t * 8;
    unsigned v[8];
    unsigned s = 0;
    #pragma unroll
    for (int j = 0; j < 8; ++j) {
        unsigned c = (ebase + j < N) ? cnt[ebase + j] : 0u;
        v[j] = s; s += c;
    }
    ts[t] = s;
    __syncthreads();
    #pragma unroll
    for (int off = 1; off < 256; off <<= 1) {
        unsigned add = (t >= off) ? ts[t - off] : 0u;
        __syncthreads();
        ts[t] += add;
        __syncthreads();
    }
    unsigned tb = (t > 0) ? ts[t - 1] : 0u;
    #pragma unroll
    for (int j = 0; j < 8; ++j)
        if (ebase + j < N) offs[ebase + j] = tb + v[j];
    if (t == 255) partials[blockIdx.x] = ts[255];
}

// inline exclusive scan of chunk partials (<=64 entries) into LDS
__device__ __forceinline__ void scan_partials_lds(
    const unsigned* __restrict__ partials, unsigned* psc, int n, int t)
{
    __shared__ unsigned raw[64];
    if (t < n) raw[t] = partials[t];
    __syncthreads();
    if (t == 0) {
        unsigned s = 0;
        for (int i = 0; i < n; ++i) { unsigned c = raw[i]; psc[i] = s; s += c; }
    }
    __syncthreads();
}

// ---------------- A3: scatter edges into bucket-grouped storage -------------
__global__ __launch_bounds__(256) void k_bin_scatter(
    const int* __restrict__ srcv, const int* __restrict__ dstv,
    const unsigned* __restrict__ bbaseT, const unsigned* __restrict__ partials,
    int nChunks, unsigned* __restrict__ binned, int E, int EPB, int NB)
{
    __shared__ unsigned cur[512];
    __shared__ unsigned psc[64];
    int t = threadIdx.x;
    scan_partials_lds(partials, psc, nChunks, t);
    for (int i = t; i < NB; i += 256) {
        unsigned idx = (unsigned)i * NBLK + blockIdx.x;
        cur[i] = bbaseT[idx] + psc[idx >> 11];
    }
    __syncthreads();
    int lo = blockIdx.x * EPB, hi = min(E, lo + EPB);
    for (int e = lo + t; e < hi; e += 256) {
        unsigned d = (unsigned)dstv[e];
        unsigned s = (unsigned)srcv[e];
        unsigned p = atomicAdd(&cur[d >> LBITS], 1u);
        binned[p] = ((d & (NPB - 1u)) << SBITS) | s;
    }
}

// ---------------- A4: per-bucket CSR with 8-aligned padded node segments ----
__global__ __launch_bounds__(256) void k_bucket_csr(
    const unsigned* __restrict__ binned, const unsigned* __restrict__ bbaseT,
    const unsigned* __restrict__ partials, int nChunks,
    unsigned* __restrict__ offs, unsigned* __restrict__ cnt,
    unsigned* __restrict__ ssrc, int E, int NB, int N)
{
    __shared__ unsigned c[256];
    __shared__ unsigned ts[256];
    __shared__ unsigned psc[64];
    int k = blockIdx.x;
    int t = threadIdx.x;
    scan_partials_lds(partials, psc, nChunks, t);

    unsigned i0 = (unsigned)k * NBLK;
    unsigned bstart = bbaseT[i0] + psc[i0 >> 11];
    unsigned bend;
    if (k + 1 < NB) {
        unsigned i1 = (unsigned)(k + 1) * NBLK;
        bend = bbaseT[i1] + psc[i1 >> 11];
    } else bend = (unsigned)E;
    unsigned bstartPad = ((bstart + 7u) & ~7u) + (unsigned)BUCKET_PAD * k;

    c[t] = 0;
    __syncthreads();
    for (unsigned e = bstart + t; e < bend; e += 256)
        atomicAdd(&c[binned[e] >> SBITS], 1u);
    __syncthreads();

    unsigned myc  = c[t];
    unsigned mycp = (myc + 7u) & ~7u;        // padded to 8
    ts[t] = mycp;
    __syncthreads();
    #pragma unroll
    for (int off = 1; off < 256; off <<= 1) {
        unsigned add = (t >= off) ? ts[t - off] : 0u;
        __syncthreads();
        ts[t] += add;
        __syncthreads();
    }
    unsigned exclp = t ? ts[t - 1] : 0u;
    unsigned stPad = bstartPad + exclp;

    int gn = k * NPB + t;
    if (gn < N) { offs[gn] = stPad; cnt[gn] = myc; }

    c[t] = exclp;          // local padded cursor
    __syncthreads();
    for (unsigned e = bstart + t; e < bend; e += 256) {
        unsigned u  = binned[e];
        unsigned ld = u >> SBITS;
        unsigned r  = atomicAdd(&c[ld], 1u);
        ssrc[bstartPad + r] = u & ((1u << SBITS) - 1u);
    }
    __syncthreads();
    // pad fill: duplicate last id (sum compensated in gather; max unaffected)
    if (myc && mycp > myc) {
        unsigned lastId = ssrc[stPad + myc - 1];
        for (unsigned j = myc; j < mycp; ++j) ssrc[stPad + j] = lastId;
    }
}

// ---------------- Phase B: gather, lane = CHANNEL PAIR, 2 edges/load --------
// Wave = node, grid-stride. Lanes 0-31 process the even edge of each pair,
// lanes 32-63 the odd edge; each lane loads one dword = 2 bf16 channels of
// its edge's 128B row. One load covers 2 edges. Cross-half combine:
// 4 x shfl_xor(32). Pads compensated via s -= p*last.
// NOTE (r14 lesson): keep this kernel de-fused and wave-independent —
// coupling it to LDS tiles / MFMA epilogues collapses occupancy and
// serializes the per-node latency chains (114 -> 255 us).
__global__ __launch_bounds__(256) void k_gather5(
    const ushort*   __restrict__ xb,      // [N][64] bf16
    const unsigned* __restrict__ ssrc,
    const unsigned* __restrict__ offs,
    const unsigned* __restrict__ cnt,
    ushort*         __restrict__ feats,   // [N][128] bf16
    int N)
{
    const unsigned* xw = reinterpret_cast<const unsigned*>(xb);  // row = 32 dwords
    unsigned* fw = reinterpret_cast<unsigned*>(feats);           // row = 64 dwords

    int tid  = threadIdx.x;
    unsigned lane = tid & 63;
    unsigned l31  = lane & 31;
    bool     hi   = lane >= 32;
    int wv   = tid >> 6;

    int nq = (N + 3) >> 2;
    for (int q = blockIdx.x; q < nq; q += gridDim.x) {
        int n = q * 4 + wv;
        if (n >= N) continue;

        unsigned st  = offs[n];
        unsigned dg  = cnt[n];
        unsigned dgp = (dg + 7u) & ~7u;

        float se0 = 0.f, so0 = 0.f, se1 = 0.f, so1 = 0.f;
        float me0 = -INFINITY, mo0 = -INFINITY, me1 = -INFINITY, mo1 = -INFINITY;

        unsigned i = 0;
        for (; i + 16 <= dgp; i += 16) {          // 16 edges = 8 pair-loads
            uint4 ia = *reinterpret_cast<const uint4*>(ssrc + st + i);
            uint4 ib = *reinterpret_cast<const uint4*>(ssrc + st + i + 4);
            uint4 ic = *reinterpret_cast<const uint4*>(ssrc + st + i + 8);
            uint4 id = *reinterpret_cast<const uint4*>(ssrc + st + i + 12);
            unsigned p0 = hi ? ia.y : ia.x;
            unsigned p1 = hi ? ia.w : ia.z;
            unsigned p2 = hi ? ib.y : ib.x;
            unsigned p3 = hi ? ib.w : ib.z;
            unsigned p4 = hi ? ic.y : ic.x;
            unsigned p5 = hi ? ic.w : ic.z;
            unsigned p6 = hi ? id.y : id.x;
            unsigned p7 = hi ? id.w : id.z;
            unsigned w0 = xw[(p0 << 5) | l31];
            unsigned w1 = xw[(p1 << 5) | l31];
            unsigned w2 = xw[(p2 << 5) | l31];
            unsigned w3 = xw[(p3 << 5) | l31];
            unsigned w4 = xw[(p4 << 5) | l31];
            unsigned w5 = xw[(p5 << 5) | l31];
            unsigned w6 = xw[(p6 << 5) | l31];
            unsigned w7 = xw[(p7 << 5) | l31];
            #pragma unroll
            for (int j = 0; j < 8; ++j) {
                unsigned w = (j==0)?w0:(j==1)?w1:(j==2)?w2:(j==3)?w3:
                             (j==4)?w4:(j==5)?w5:(j==6)?w6:w7;
                float fe = __uint_as_float(w << 16);
                float fo = __uint_as_float(w & 0xFFFF0000u);
                if (j & 1) {
                    se1 += fe; so1 += fo;
                    me1 = fmaxf(me1, fe); mo1 = fmaxf(mo1, fo);
                } else {
                    se0 += fe; so0 += fo;
                    me0 = fmaxf(me0, fe); mo0 = fmaxf(mo0, fo);
                }
            }
        }
        if (i < dgp) {                             // one 8-edge batch = 4 pairs
            uint4 ia = *reinterpret_cast<const uint4*>(ssrc + st + i);
            uint4 ib = *reinterpret_cast<const uint4*>(ssrc + st + i + 4);
            unsigned p0 = hi ? ia.y : ia.x;
            unsigned p1 = hi ? ia.w : ia.z;
            unsigned p2 = hi ? ib.y : ib.x;
            unsigned p3 = hi ? ib.w : ib.z;
            unsigned w0 = xw[(p0 << 5) | l31];
            unsigned w1 = xw[(p1 << 5) | l31];
            unsigned w2 = xw[(p2 << 5) | l31];
            unsigned w3 = xw[(p3 << 5) | l31];
            #pragma unroll
            for (int j = 0; j < 4; ++j) {
                unsigned w = (j==0)?w0:(j==1)?w1:(j==2)?w2:w3;
                float fe = __uint_as_float(w << 16);
                float fo = __uint_as_float(w & 0xFFFF0000u);
                if (j & 1) {
                    se1 += fe; so1 += fo;
                    me1 = fmaxf(me1, fe); mo1 = fmaxf(mo1, fo);
                } else {
                    se0 += fe; so0 += fo;
                    me0 = fmaxf(me0, fe); mo0 = fmaxf(mo0, fo);
                }
            }
        }

        float se = se0 + se1, so = so0 + so1;
        float me = fmaxf(me0, me1), mo = fmaxf(mo0, mo1);
        se += __shfl_xor(se, 32);
        so += __shfl_xor(so, 32);
        me = fmaxf(me, __shfl_xor(me, 32));
        mo = fmaxf(mo, __shfl_xor(mo, 32));

        unsigned p = dgp - dg;
        if (p && dg) {                             // pad compensation
            unsigned lastId = ssrc[st + dg - 1];
            unsigned w = xw[(lastId << 5) | l31];
            se -= (float)p * __uint_as_float(w << 16);
            so -= (float)p * __uint_as_float(w & 0xFFFF0000u);
        }
        if (!dg) { me = 0.0f; mo = 0.0f; }

        float v0 = hi ? me : se;
        float v1 = hi ? mo : so;
        unsigned outw = ((unsigned)f2bf(v0)) | (((unsigned)f2bf(v1)) << 16);
        fw[((size_t)n << 6) | lane] = outw;
    }
}

// ---------------- Phase C: MFMA MLP ----------------
__global__ __launch_bounds__(256) void k_mlp2(
    const ushort*   __restrict__ feats,   // [N][128] bf16
    const unsigned* __restrict__ cnt,
    const ushort*   __restrict__ Wb,      // [64][192] bf16
    const float*    __restrict__ bias,    // [64]
    float*          __restrict__ out,     // [N][64]
    int N)
{
    int tid  = threadIdx.x;
    int lane = tid & 63;
    int wv   = tid >> 6;
    int l16  = lane & 15;
    int kb   = (lane >> 4) << 3;

    int col = (wv << 4) + l16;
    const ushort* wp = Wb + (size_t)col * F3 + kb;
    bf16x8 bS0 = *reinterpret_cast<const bf16x8*>(wp);
    bf16x8 bS1 = *reinterpret_cast<const bf16x8*>(wp + 32);
    bf16x8 bM0 = *reinterpret_cast<const bf16x8*>(wp + 64);
    bf16x8 bM1 = *reinterpret_cast<const bf16x8*>(wp + 96);
    bf16x8 bX0 = *reinterpret_cast<const bf16x8*>(wp + 128);
    bf16x8 bX1 = *reinterpret_cast<const bf16x8*>(wp + 160);
    float bo = bias[col];

    int n0 = blockIdx.x << 4;            // N divisible by 16

    unsigned dgr = cnt[n0 + l16];
    float inv = dgr ? 1.0f / (float)dgr : 0.0f;

    const ushort* arow = feats + (size_t)(n0 + l16) * FS + kb;
    bf16x8 aS0 = *reinterpret_cast<const bf16x8*>(arow);
    bf16x8 aS1 = *reinterpret_cast<const bf16x8*>(arow + 32);
    bf16x8 aX0 = *reinterpret_cast<const bf16x8*>(arow + 64);
    bf16x8 aX1 = *reinterpret_cast<const bf16x8*>(arow + 96);

    bf16x8 aM0, aM1;
    #pragma unroll
    for (int j = 0; j < 8; ++j) {
        aM0[j] = (short)f2bf(bf2f((ushort)aS0[j]) * inv);
        aM1[j] = (short)f2bf(bf2f((ushort)aS1[j]) * inv);
    }

    f32x4 acc = { bo, bo, bo, bo };
    acc = __builtin_amdgcn_mfma_f32_16x16x32_bf16(aS0, bS0, acc, 0, 0, 0);
    acc = __builtin_amdgcn_mfma_f32_16x16x32_bf16(aS1, bS1, acc, 0, 0, 0);
    acc = __builtin_amdgcn_mfma_f32_16x16x32_bf16(aM0, bM0, acc, 0, 0, 0);
    acc = __builtin_amdgcn_mfma_f32_16x16x32_bf16(aM1, bM1, acc, 0, 0, 0);
    acc = __builtin_amdgcn_mfma_f32_16x16x32_bf16(aX0, bX0, acc, 0, 0, 0);
    acc = __builtin_amdgcn_mfma_f32_16x16x32_bf16(aX1, bX1, acc, 0, 0, 0);

    int rbase = n0 + ((lane >> 4) << 2);
    #pragma unroll
    for (int r = 0; r < 4; ++r)
        out[(size_t)(rbase + r) * D + col] = acc[r];
}

extern "C" void kernel_launch(void* const* d_in, const int* in_sizes, int n_in,
                              void* d_out, int out_size, void* d_ws, size_t ws_size,
                              hipStream_t stream)
{
    const float* x  = (const float*)d_in[0];
    const int*   ei = (const int*)d_in[1];
    const float* W  = (const float*)d_in[2];
    const float* b  = (const float*)d_in[3];
    float* out = (float*)d_out;

    int N = in_sizes[0] / D;
    int E = in_sizes[1] / 2;
    const int* srcv = ei;
    const int* dstv = ei + E;

    int NB  = (N + NPB - 1) / NPB;          // 391 buckets
    int EPB = (E + NBLK - 1) / NBLK;
    int M   = NB * NBLK;                    // 100096

    unsigned* bcntT    = (unsigned*)d_ws;          // [M]       400KB
    unsigned* bbaseT   = bcntT + M;                // [M]       400KB
    unsigned* partials = bbaseT + M;               // [64]
    unsigned* offs     = partials + 64;            // [N]       400KB
    unsigned* cnt      = offs + N;                 // [N]       400KB
    unsigned* ssrc     = cnt + N;                  // [SSRC_CAP] 8MB (padded)
    ushort*   xb       = (ushort*)(ssrc + SSRC_CAP);   // [N*64]  12.8MB
    ushort*   Wb       = xb + (size_t)N * D;           // [64*192]
    ushort*   feats    = Wb + (size_t)D * F3;          // [N*128] 25.6MB
    unsigned* binned   = (unsigned*)feats;             // [E] aliases feats (dead before gather)

    int nChunksM  = (M + SCAN_CHUNK - 1) / SCAN_CHUNK;  // 49
    int n4        = N * D / 4;
    int castBlocks = (n4 + 255) / 256;

    k_cast_hist<<<NBLK + castBlocks + 1, 256, 0, stream>>>(
        x, xb, n4, W, Wb, D * F3, dstv, bcntT, E, EPB, NB, castBlocks);
    k_chunk_scan<<<nChunksM, 256, 0, stream>>>(bcntT, bbaseT, partials, M);
    k_bin_scatter<<<NBLK, 256, 0, stream>>>(srcv, dstv, bbaseT, partials,
                                            nChunksM, binned, E, EPB, NB);
    k_bucket_csr<<<NB, 256, 0, stream>>>(binned, bbaseT, partials, nChunksM,
                                         offs, cnt, ssrc, E, NB, N);
    k_gather5<<<2048, 256, 0, stream>>>(xb, ssrc, offs, cnt, feats, N);
    k_mlp2<<<N / 16, 256, 0, stream>>>(feats, cnt, Wb, b, out, N);
}